// Round 16
// baseline (168.329 us; speedup 1.0000x reference)
//
#include <hip/hip_runtime.h>
#include <math.h>

#define BB 8
#define SS 512
#define MM 512
#define TT 1024
#define DD 1024
#define HH 16
#define DH 64

typedef __attribute__((ext_vector_type(8))) short bf16x8;
typedef __attribute__((ext_vector_type(4))) float f32x4;

#define SCL2E 0.1803368801111f  /* 0.125 * log2(e) */
#define DTHR 11.5f              /* defer-max threshold in log2 units */

__device__ __forceinline__ ushort f2bf(float f) {
  union { float f; unsigned u; } x; x.f = f;
  unsigned r = x.u + 0x7fffu + ((x.u >> 16) & 1u);
  return (ushort)(r >> 16);
}
__device__ __forceinline__ float bf2f(ushort u) {
  return __builtin_bit_cast(float, ((unsigned)u) << 16);
}

__device__ __forceinline__ void stage16(void* lds, const void* g) {
  __builtin_amdgcn_global_load_lds((const __attribute__((address_space(1))) void*)g,
                                   (__attribute__((address_space(3))) void*)lds, 16, 0, 0);
}

template <int C>
__device__ __forceinline__ float dppf(float x) {
  return __builtin_bit_cast(float,
      __builtin_amdgcn_update_dpp(0, __builtin_bit_cast(int, x), C, 0xF, 0xF, true));
}
__device__ __forceinline__ float redmax16(float x) {
  x = fmaxf(x, dppf<0xB1>(x));
  x = fmaxf(x, dppf<0x4E>(x));
  x = fmaxf(x, dppf<0x141>(x));
  x = fmaxf(x, dppf<0x140>(x));
  return x;
}
__device__ __forceinline__ float redsum16(float x) {
  x += dppf<0xB1>(x);
  x += dppf<0x4E>(x);
  x += dppf<0x141>(x);
  x += dppf<0x140>(x);
  return x;
}
__device__ __forceinline__ float bperm_f(int byteaddr, float v) {
  return __builtin_bit_cast(float,
      __builtin_amdgcn_ds_bpermute(byteaddr, __builtin_bit_cast(int, v)));
}

// ---------------------------------------------------------------------------
// Fused fp32->bf16 casts (segment decode per block range).
// ---------------------------------------------------------------------------
__global__ __launch_bounds__(256) void cast_all(
    const float* __restrict__ mem, const float* __restrict__ x,
    const float* __restrict__ R, const float* __restrict__ Wq,
    const float* __restrict__ Wk, const float* __restrict__ Wv,
    const float* __restrict__ Wr, const float* __restrict__ Wo,
    ushort* __restrict__ hb, ushort* __restrict__ Rb, ushort* __restrict__ Wqb,
    ushort* __restrict__ Wkb, ushort* __restrict__ Wvb, ushort* __restrict__ Wrb,
    ushort* __restrict__ Wob) {
  const int M1 = 1 << 20;
  int i = (blockIdx.x * 256 + threadIdx.x) * 8;
  const float* src;
  ushort* dst;
  if (i < 4 * M1) {
    src = mem + i;
    dst = hb + (size_t)i + (size_t)(i >> 19) * 524288;
  } else if (i < 8 * M1) {
    int j = i - 4 * M1;
    src = x + j;
    dst = hb + (size_t)j + (size_t)(j >> 19) * 524288 + 524288;
  } else if (i < 9 * M1) {
    src = R + (i - 8 * M1);  dst = Rb + (i - 8 * M1);
  } else if (i < 10 * M1) {
    src = Wq + (i - 9 * M1); dst = Wqb + (i - 9 * M1);
  } else if (i < 11 * M1) {
    src = Wk + (i - 10 * M1); dst = Wkb + (i - 10 * M1);
  } else if (i < 12 * M1) {
    src = Wv + (i - 11 * M1); dst = Wvb + (i - 11 * M1);
  } else if (i < 13 * M1) {
    src = Wr + (i - 12 * M1); dst = Wrb + (i - 12 * M1);
  } else {
    src = Wo + (i - 13 * M1); dst = Wob + (i - 13 * M1);
  }
  float4 a = *(const float4*)(src);
  float4 c = *(const float4*)(src + 4);
  union { bf16x8 v; ushort u[8]; } pk;
  pk.u[0] = f2bf(a.x); pk.u[1] = f2bf(a.y); pk.u[2] = f2bf(a.z); pk.u[3] = f2bf(a.w);
  pk.u[4] = f2bf(c.x); pk.u[5] = f2bf(c.y); pk.u[6] = f2bf(c.z); pk.u[7] = f2bf(c.w);
  *(bf16x8*)(void*)dst = pk.v;
}

// ---------------------------------------------------------------------------
// Fused q / (k+v) / r projection GEMM. 832 blocks = 256 q + 512 kv + 64 r.
// kv blocks compute BOTH k[mt][nx] and v[mt][nx]: the A-tile is staged once
// per K-step and each counted-drain window covers 32 MFMA (was 16).
// Per phase (kv): stage {A, Wk, Wv} (6 loads) -> vmcnt(6) -> s_barrier ->
// compute both accs -> s_barrier. q/r keep the r14 4-load/vmcnt(4) pipeline.
// BK=32, 2-bit chunk swizzle (conflicts=0, r11), bijective XCD swizzle
// (832 = 8*104). v written TRANSPOSED.
// ---------------------------------------------------------------------------
__global__ __launch_bounds__(256, 2) void gemm_qkvr(
    const ushort* __restrict__ hb, const ushort* __restrict__ Rbuf,
    const ushort* __restrict__ Wqb, const ushort* __restrict__ Wkb,
    const ushort* __restrict__ Wvb, const ushort* __restrict__ Wrb,
    ushort* __restrict__ qub,
    ushort* __restrict__ kbo, ushort* __restrict__ vtb, ushort* __restrict__ rbo,
    const float* __restrict__ uvec) {
  __shared__ ushort As0[4096], As1[4096], Bk0[4096], Bk1[4096], Bv0[4096], Bv1[4096];
  const int bid = (blockIdx.x & 7) * 104 + (blockIdx.x >> 3);
  const ushort* A;
  const ushort* Wk_;
  const ushort* Wv_ = nullptr;
  ushort* C0 = nullptr;
  ushort* C1 = nullptr;
  bool qadd = false, qslice = false, kvmode = false;
  int mt, nx;
  if (bid < 256) {
    mt = bid >> 3; nx = bid & 7;
    A = hb; Wk_ = Wqb; C0 = qub; qadd = true; qslice = true;
  } else if (bid < 768) {
    int r2 = bid - 256; mt = r2 >> 3; nx = r2 & 7;
    A = hb; Wk_ = Wkb; Wv_ = Wvb; C0 = kbo; C1 = vtb; kvmode = true;
  } else {
    int r2 = bid - 768; mt = r2 >> 3; nx = r2 & 7;
    A = Rbuf; Wk_ = Wrb; C0 = rbo;
  }
  const int m0 = mt * 128, n0 = nx * 128;

  const int t = threadIdx.x;
  const int w = t >> 6, l = t & 63;
  const int m16 = l & 15, kg = l >> 4;
  const int wr = w >> 1, wc = w & 1;

  const int c0 = t, c1 = t + 256;
  const int scol = (((t & 3) ^ ((t >> 3) & 3)) * 8);
  const ushort* asrc0;
  const ushort* asrc1;
  {
    int gm0 = m0 + (c0 >> 2), gm1 = m0 + (c1 >> 2);
    if (qslice) {
      asrc0 = A + ((size_t)((gm0 >> 9) * TT + MM + (gm0 & 511))) * DD + scol;
      asrc1 = A + ((size_t)((gm1 >> 9) * TT + MM + (gm1 & 511))) * DD + scol;
    } else {
      asrc0 = A + (size_t)gm0 * DD + scol;
      asrc1 = A + (size_t)gm1 * DD + scol;
    }
  }
  const ushort* bksrc0 = Wk_ + (size_t)(n0 + (c0 >> 2)) * DD + scol;
  const ushort* bksrc1 = Wk_ + (size_t)(n0 + (c1 >> 2)) * DD + scol;
  const ushort* bvsrc0 = kvmode ? Wv_ + (size_t)(n0 + (c0 >> 2)) * DD + scol : nullptr;
  const ushort* bvsrc1 = kvmode ? Wv_ + (size_t)(n0 + (c1 >> 2)) * DD + scol : nullptr;

  const int cbx = ((kg ^ ((m16 >> 1) & 3)) << 3);
  const int arow0 = (wr * 64 + m16) * 32 + cbx;
  const int brow0 = (wc * 64 + m16) * 32 + cbx;

  f32x4 acck[4][4], accv[4][4];
#pragma unroll
  for (int mi = 0; mi < 4; ++mi)
#pragma unroll
    for (int ni = 0; ni < 4; ++ni) {
      acck[mi][ni] = (f32x4){0.f, 0.f, 0.f, 0.f};
      accv[mi][ni] = (f32x4){0.f, 0.f, 0.f, 0.f};
    }

#define ST4(AS, BS, KOFF)                       \
  do {                                          \
    stage16(AS + c0 * 8, asrc0 + (KOFF));       \
    stage16(AS + c1 * 8, asrc1 + (KOFF));       \
    stage16(BS + c0 * 8, bksrc0 + (KOFF));      \
    stage16(BS + c1 * 8, bksrc1 + (KOFF));      \
  } while (0)

#define ST6(AS, BS, BV, KOFF)                   \
  do {                                          \
    ST4(AS, BS, KOFF);                          \
    stage16(BV + c0 * 8, bvsrc0 + (KOFF));      \
    stage16(BV + c1 * 8, bvsrc1 + (KOFF));      \
  } while (0)

#define CMP1(AS, BS)                                                              \
  do {                                                                            \
    bf16x8 af[4], bfr[4];                                                         \
    _Pragma("unroll") for (int mi = 0; mi < 4; ++mi)                              \
        af[mi] = *(const bf16x8*)(const void*)&AS[arow0 + mi * 512];              \
    _Pragma("unroll") for (int ni = 0; ni < 4; ++ni)                              \
        bfr[ni] = *(const bf16x8*)(const void*)&BS[brow0 + ni * 512];             \
    _Pragma("unroll") for (int mi = 0; mi < 4; ++mi)                              \
        _Pragma("unroll") for (int ni = 0; ni < 4; ++ni)                          \
            acck[mi][ni] = __builtin_amdgcn_mfma_f32_16x16x32_bf16(               \
                af[mi], bfr[ni], acck[mi][ni], 0, 0, 0);                          \
  } while (0)

#define CMP2(AS, BS, BV)                                                          \
  do {                                                                            \
    bf16x8 af[4], bfk[4], bfv[4];                                                 \
    _Pragma("unroll") for (int mi = 0; mi < 4; ++mi)                              \
        af[mi] = *(const bf16x8*)(const void*)&AS[arow0 + mi * 512];              \
    _Pragma("unroll") for (int ni = 0; ni < 4; ++ni)                              \
        bfk[ni] = *(const bf16x8*)(const void*)&BS[brow0 + ni * 512];             \
    _Pragma("unroll") for (int ni = 0; ni < 4; ++ni)                              \
        bfv[ni] = *(const bf16x8*)(const void*)&BV[brow0 + ni * 512];             \
    _Pragma("unroll") for (int mi = 0; mi < 4; ++mi)                              \
        _Pragma("unroll") for (int ni = 0; ni < 4; ++ni)                          \
            acck[mi][ni] = __builtin_amdgcn_mfma_f32_16x16x32_bf16(               \
                af[mi], bfk[ni], acck[mi][ni], 0, 0, 0);                          \
    _Pragma("unroll") for (int mi = 0; mi < 4; ++mi)                              \
        _Pragma("unroll") for (int ni = 0; ni < 4; ++ni)                          \
            accv[mi][ni] = __builtin_amdgcn_mfma_f32_16x16x32_bf16(               \
                af[mi], bfv[ni], accv[mi][ni], 0, 0, 0);                          \
  } while (0)

  if (kvmode) {
    ST6(As0, Bk0, Bv0, 0);
#pragma unroll 1
    for (int kt = 0; kt < 32; kt += 2) {
      ST6(As1, Bk1, Bv1, (kt + 1) << 5);
      asm volatile("s_waitcnt vmcnt(6)" ::: "memory");
      __builtin_amdgcn_s_barrier();
      CMP2(As0, Bk0, Bv0);
      __builtin_amdgcn_s_barrier();
      if (kt + 2 < 32) {
        ST6(As0, Bk0, Bv0, (kt + 2) << 5);
        asm volatile("s_waitcnt vmcnt(6)" ::: "memory");
      } else {
        asm volatile("s_waitcnt vmcnt(0)" ::: "memory");
      }
      __builtin_amdgcn_s_barrier();
      CMP2(As1, Bk1, Bv1);
      __builtin_amdgcn_s_barrier();
    }
  } else {
    ST4(As0, Bk0, 0);
#pragma unroll 1
    for (int kt = 0; kt < 32; kt += 2) {
      ST4(As1, Bk1, (kt + 1) << 5);
      asm volatile("s_waitcnt vmcnt(4)" ::: "memory");
      __builtin_amdgcn_s_barrier();
      CMP1(As0, Bk0);
      __builtin_amdgcn_s_barrier();
      if (kt + 2 < 32) {
        ST4(As0, Bk0, (kt + 2) << 5);
        asm volatile("s_waitcnt vmcnt(4)" ::: "memory");
      } else {
        asm volatile("s_waitcnt vmcnt(0)" ::: "memory");
      }
      __builtin_amdgcn_s_barrier();
      CMP1(As1, Bk1);
      __builtin_amdgcn_s_barrier();
    }
  }
#undef ST4
#undef ST6
#undef CMP1
#undef CMP2

  const int rbase = m0 + wr * 64 + kg * 4;
  const int cbase = n0 + wc * 64 + m16;
  if (kvmode) {
    // k: normal store
#pragma unroll
    for (int mi = 0; mi < 4; ++mi)
#pragma unroll
      for (int ni = 0; ni < 4; ++ni)
#pragma unroll
        for (int rg = 0; rg < 4; ++rg)
          C0[(size_t)(rbase + mi * 16 + rg) * DD + cbase + ni * 16] = f2bf(acck[mi][ni][rg]);
    // v: transposed store vt[(b*1024 + col)][t]
    const int bb = m0 >> 10;
    const int tt0 = (m0 & 1023) + wr * 64 + kg * 4;
#pragma unroll
    for (int mi = 0; mi < 4; ++mi)
#pragma unroll
      for (int ni = 0; ni < 4; ++ni) {
        ushort4 o;
        o.x = f2bf(accv[mi][ni][0]); o.y = f2bf(accv[mi][ni][1]);
        o.z = f2bf(accv[mi][ni][2]); o.w = f2bf(accv[mi][ni][3]);
        *(ushort4*)(C1 + ((size_t)(bb * 1024 + cbase + ni * 16) << 10) + tt0 + mi * 16) = o;
      }
  } else if (qadd) {
    float uv[4];
#pragma unroll
    for (int ni = 0; ni < 4; ++ni) uv[ni] = uvec[cbase + ni * 16];
#pragma unroll
    for (int mi = 0; mi < 4; ++mi)
#pragma unroll
      for (int ni = 0; ni < 4; ++ni)
#pragma unroll
        for (int rg = 0; rg < 4; ++rg)
          C0[(size_t)(rbase + mi * 16 + rg) * DD + cbase + ni * 16] = f2bf(acck[mi][ni][rg] + uv[ni]);
  } else {
#pragma unroll
    for (int mi = 0; mi < 4; ++mi)
#pragma unroll
      for (int ni = 0; ni < 4; ++ni)
#pragma unroll
        for (int rg = 0; rg < 4; ++rg)
          C0[(size_t)(rbase + mi * 16 + rg) * DD + cbase + ni * 16] = f2bf(acck[mi][ni][rg]);
  }
}

// ---------------------------------------------------------------------------
// MFMA GEMM for Wo: 128x64 tiles -> 512 blocks (r12/r14-verified).
// ---------------------------------------------------------------------------
__global__ __launch_bounds__(256) void gemm_wo(const ushort* __restrict__ A,
                                               const ushort* __restrict__ W,
                                               ushort* __restrict__ Cb) {
  __shared__ ushort As[128 * 32];
  __shared__ ushort Bs[64 * 32];
  const int bid = (blockIdx.x & 7) * 64 + (blockIdx.x >> 3);
  const int mt = bid >> 4, nxt = bid & 15;
  const int m0 = mt * 128, n0 = nxt * 64;
  const int t = threadIdx.x;
  const int w = t >> 6, l = t & 63;
  const int m16 = l & 15, kg = l >> 4;
  const int wr = w >> 1, wc = w & 1;

  const int scol = (((t & 3) ^ ((t >> 3) & 3)) * 8);
  const ushort* asrc0 = A + (size_t)(m0 + (t >> 2)) * DD + scol;
  const ushort* asrc1 = A + (size_t)(m0 + 64 + (t >> 2)) * DD + scol;
  const ushort* bsrc0 = W + (size_t)(n0 + (t >> 2)) * DD + scol;
  ushort* adst0 = As + t * 8;
  ushort* adst1 = As + (t + 256) * 8;
  ushort* bdst0 = Bs + t * 8;

  const int cbx = ((kg ^ ((m16 >> 1) & 3)) << 3);

  f32x4 acc[4][2];
#pragma unroll
  for (int mi = 0; mi < 4; ++mi)
#pragma unroll
    for (int ni = 0; ni < 2; ++ni) acc[mi][ni] = (f32x4){0.f, 0.f, 0.f, 0.f};

  for (int k0 = 0; k0 < DD; k0 += 32) {
    stage16(adst0, asrc0 + k0);
    stage16(adst1, asrc1 + k0);
    stage16(bdst0, bsrc0 + k0);
    __syncthreads();
    bf16x8 af[4], bfr[2];
#pragma unroll
    for (int mi = 0; mi < 4; ++mi)
      af[mi] = *(const bf16x8*)(const void*)&As[(wr * 64 + mi * 16 + m16) * 32 + cbx];
#pragma unroll
    for (int ni = 0; ni < 2; ++ni)
      bfr[ni] = *(const bf16x8*)(const void*)&Bs[(wc * 32 + ni * 16 + m16) * 32 + cbx];
#pragma unroll
    for (int mi = 0; mi < 4; ++mi)
#pragma unroll
      for (int ni = 0; ni < 2; ++ni)
        acc[mi][ni] = __builtin_amdgcn_mfma_f32_16x16x32_bf16(af[mi], bfr[ni], acc[mi][ni], 0, 0, 0);
    __syncthreads();
  }

  const int rbase = m0 + wr * 64 + kg * 4;
  const int cbase = n0 + wc * 32 + m16;
#pragma unroll
  for (int mi = 0; mi < 4; ++mi)
#pragma unroll
    for (int ni = 0; ni < 2; ++ni)
#pragma unroll
      for (int rg = 0; rg < 4; ++rg)
        Cb[(size_t)(rbase + mi * 16 + rg) * DD + cbase + ni * 16] = f2bf(acc[mi][ni][rg]);
}

// ---------------------------------------------------------------------------
// MFMA flash attention: counted-vmcnt 2-phase pipeline (r15-verified).
// ---------------------------------------------------------------------------
__global__ __launch_bounds__(256) void attn_mfma(const ushort* __restrict__ qu,
                                                 const ushort* __restrict__ kb,
                                                 const ushort* __restrict__ vt,
                                                 const ushort* __restrict__ rb,
                                                 const float* __restrict__ uvec,
                                                 const float* __restrict__ tvec,
                                                 ushort* __restrict__ att) {
  const int w = threadIdx.x >> 6;
  const int l = threadIdx.x & 63;
  const int m16 = l & 15;
  const int kg = l >> 4;
  const int bid = blockIdx.x;
  const int it = 7 - (bid >> 7);         // longest (ntj=16) first
  const int bh = bid & 127;
  const int b = bh >> 4, h = bh & 15;
  const int i0 = it * 64;

  __shared__ ushort Ks0[4096], Ks1[4096];
  __shared__ ushort Vs0[4096], Vs1[4096];
  __shared__ ushort Rl[16384];
  __shared__ ushort plds[4][16][72];

  bf16x8 aqu[2], aqt[2];
  {
    const ushort* qrow = qu + ((size_t)(b * SS + i0 + w * 16 + m16)) * DD + h * DH + kg * 8;
    aqu[0] = *(const bf16x8*)(const void*)(qrow);
    aqu[1] = *(const bf16x8*)(const void*)(qrow + 32);
#pragma unroll
    for (int ks = 0; ks < 2; ++ks) {
      ushort* a = (ushort*)&aqt[ks];
      const ushort* qa = (const ushort*)&aqu[ks];
#pragma unroll
      for (int e = 0; e < 8; ++e) {
        const int col = h * DH + kg * 8 + ks * 32 + e;
        a[e] = f2bf(bf2f(qa[e]) + (tvec[col] - uvec[col]));
      }
    }
  }

  int baddr[4];
  bool bsel[4];
#pragma unroll
  for (int rg = 0; rg < 4; ++rg) {
    const int rw = kg * 4 + rg;
    baddr[rg] = (kg * 16 + ((m16 + 15 - rw) & 15)) << 2;
    bsel[rg] = m16 > rw;
  }

  const int c0 = threadIdx.x, c1 = threadIdx.x + 256;
  const int r0 = c0 >> 3, sc0 = ((c0 & 7) * 8) ^ ((r0 & 7) << 3);
  const int r1 = c1 >> 3, sc1 = ((c1 & 7) * 8) ^ ((r1 & 7) << 3);
  const ushort* kp0 = kb + ((size_t)(b * TT) + r0) * DD + h * DH + sc0;
  const ushort* kp1 = kb + ((size_t)(b * TT) + r1) * DD + h * DH + sc1;
  const ushort* vp0 = vt + ((size_t)(b * 1024 + h * DH + r0)) * 1024 + sc0;
  const ushort* vp1 = vt + ((size_t)(b * 1024 + h * DH + r1)) * 1024 + sc1;

  const int cb0 = (kg * 8) ^ ((m16 & 7) << 3);
  const int cb1 = (kg * 8 + 32) ^ ((m16 & 7) << 3);
  int slot64[5];
#pragma unroll
  for (int f = 0; f < 5; ++f)
    slot64[f] = ((496 - i0 - w * 16 + m16 + f * 16) & 255) << 6;

  {
    const int base0 = 448 - i0;
#pragma unroll
    for (int kk = 0; kk < 4; ++kk) {
      int c = threadIdx.x + kk * 256;
      int ro = c >> 3, cc = c & 7;
      int p = base0 + ro;
      int slot = p & 255;
      stage16(Rl + slot * 64 + cc * 8,
              rb + (size_t)p * DD + h * DH + ((cc * 8) ^ ((ro & 7) << 3)));
    }
  }
  stage16(Ks0 + c0 * 8, kp0);
  stage16(Ks0 + c1 * 8, kp1);
  stage16(Vs0 + c0 * 8, vp0);
  stage16(Vs0 + c1 * 8, vp1);
  kp0 += (size_t)64 * DD; kp1 += (size_t)64 * DD;
  vp0 += 64; vp1 += 64;

  f32x4 O[4];
  float mrow[4], lrow[4];
#pragma unroll
  for (int nt = 0; nt < 4; ++nt) O[nt] = (f32x4){0.f, 0.f, 0.f, 0.f};
#pragma unroll
  for (int rg = 0; rg < 4; ++rg) { mrow[rg] = -1e30f; lrow[rg] = 0.f; }

  const int ntj = it + 9;

  auto stage_next = [&](ushort* KN, ushort* VN, int jt) {
    stage16(KN + c0 * 8, kp0);
    stage16(KN + c1 * 8, kp1);
    kp0 += (size_t)64 * DD; kp1 += (size_t)64 * DD;
    stage16(VN + c0 * 8, vp0);
    stage16(VN + c1 * 8, vp1);
    vp0 += 64; vp1 += 64;
    const int pstart = 576 + jt * 64 - i0;
#pragma unroll
    for (int kk = 0; kk < 2; ++kk) {
      int c = threadIdx.x + kk * 256;
      int ro = c >> 3, cc = c & 7;
      int p = pstart + ro;
      int pc = p < 1023 ? p : 1023;
      int slot = p & 255;
      stage16(Rl + slot * 64 + cc * 8,
              rb + (size_t)pc * DD + h * DH + ((cc * 8) ^ ((ro & 7) << 3)));
    }
  };

  auto compute_tile = [&](const ushort* kbase, const ushort* vbase, int jt) {
    const int j0 = jt * 64;
    f32x4 ac[4];
    __builtin_amdgcn_s_setprio(1);
#pragma unroll
    for (int nt = 0; nt < 4; ++nt) {
      ac[nt] = (f32x4){0.f, 0.f, 0.f, 0.f};
      const int row = nt * 16 + m16;
#pragma unroll
      for (int ks = 0; ks < 2; ++ks) {
        bf16x8 bk = *(const bf16x8*)(const void*)(kbase + row * 64 + (ks == 0 ? cb0 : cb1));
        ac[nt] = __builtin_amdgcn_mfma_f32_16x16x32_bf16(aqu[ks], bk, ac[nt], 0, 0, 0);
      }
    }
    f32x4 bd[5];
#pragma unroll
    for (int f = 0; f < 5; ++f) {
      f32x4 z = (f32x4){0.f, 0.f, 0.f, 0.f};
      bf16x8 b0 = *(const bf16x8*)(const void*)(Rl + slot64[f] + cb0);
      z = __builtin_amdgcn_mfma_f32_16x16x32_bf16(aqt[0], b0, z, 0, 0, 0);
      bf16x8 b1 = *(const bf16x8*)(const void*)(Rl + slot64[f] + cb1);
      bd[f] = __builtin_amdgcn_mfma_f32_16x16x32_bf16(aqt[1], b1, z, 0, 0, 0);
    }
    __builtin_amdgcn_s_setprio(0);
#pragma unroll
    for (int f = 0; f < 5; ++f) slot64[f] = (slot64[f] + 4096) & 16383;

    float sca[4][4];
#pragma unroll
    for (int rg = 0; rg < 4; ++rg) {
      float rr[5];
#pragma unroll
      for (int f = 0; f < 5; ++f) rr[f] = bperm_f(baddr[rg], bd[f][rg]);
#pragma unroll
      for (int nt = 0; nt < 4; ++nt) {
        float bdv = bsel[rg] ? rr[nt + 1] : rr[nt];
        sca[nt][rg] = (ac[nt][rg] + bdv) * SCL2E;
      }
    }
    if (jt == ntj - 1) {
#pragma unroll
      for (int rg = 0; rg < 4; ++rg) {
        const int jmax = i0 + w * 16 + kg * 4 + rg + MM;
#pragma unroll
        for (int nt = 0; nt < 4; ++nt)
          sca[nt][rg] = (j0 + nt * 16 + m16 <= jmax) ? sca[nt][rg] : -1e30f;
      }
    }

    float pmax[4];
#pragma unroll
    for (int rg = 0; rg < 4; ++rg) {
      float pm = fmaxf(fmaxf(sca[0][rg], sca[1][rg]), fmaxf(sca[2][rg], sca[3][rg]));
      pmax[rg] = redmax16(pm);
    }
    bool grow = false;
#pragma unroll
    for (int rg = 0; rg < 4; ++rg) grow = grow || (pmax[rg] > mrow[rg] + DTHR);
    if (__any(grow)) {
#pragma unroll
      for (int rg = 0; rg < 4; ++rg) {
        float mnew = fmaxf(mrow[rg], pmax[rg]);
        float scale = __builtin_amdgcn_exp2f(mrow[rg] - mnew);
        mrow[rg] = mnew;
        lrow[rg] *= scale;
#pragma unroll
        for (int nt = 0; nt < 4; ++nt) O[nt][rg] *= scale;
      }
    }

#pragma unroll
    for (int rg = 0; rg < 4; ++rg) {
      float ps = 0.f;
#pragma unroll
      for (int nt = 0; nt < 4; ++nt) {
        float p = __builtin_amdgcn_exp2f(sca[nt][rg] - mrow[rg]);
        ps += p;
        plds[w][kg * 4 + rg][nt * 16 + m16] = f2bf(p);
      }
      lrow[rg] += redsum16(ps);
    }

    __builtin_amdgcn_s_setprio(1);
#pragma unroll
    for (int ks = 0; ks < 2; ++ks) {
      bf16x8 pa = *(const bf16x8*)(const void*)&plds[w][m16][kg * 8 + ks * 32];
#pragma unroll
      for (int nt = 0; nt < 4; ++nt) {
        bf16x8 vf = *(const bf16x8*)(const void*)(vbase + (nt * 16 + m16) * 64 + (ks == 0 ? cb0 : cb1));
        O[nt] = __builtin_amdgcn_mfma_f32_16x16x32_bf16(pa, vf, O[nt], 0, 0, 0);
      }
    }
    __builtin_amdgcn_s_setprio(0);
  };

  int jt = 0;
  for (;;) {
    {
      if (jt + 1 < ntj) {
        stage_next(Ks1, Vs1, jt);
        asm volatile("s_waitcnt vmcnt(6)" ::: "memory");
      } else {
        asm volatile("s_waitcnt vmcnt(0)" ::: "memory");
      }
      __builtin_amdgcn_s_barrier();
      compute_tile(Ks0, Vs0, jt);
      if (jt + 1 == ntj) break;
      __builtin_amdgcn_s_barrier();
      ++jt;
    }
    {
      if (jt + 1 < ntj) {
        stage_next(Ks0, Vs0, jt);
        asm volatile("s_waitcnt vmcnt(6)" ::: "memory");
      } else {
        asm volatile("s_waitcnt vmcnt(0)" ::: "memory");
      }
      __builtin_amdgcn_s_barrier();
      compute_tile(Ks1, Vs1, jt);
      if (jt + 1 == ntj) break;
      __builtin_amdgcn_s_barrier();
      ++jt;
    }
  }

  float linv[4];
#pragma unroll
  for (int rg = 0; rg < 4; ++rg) linv[rg] = 1.f / lrow[rg];
#pragma unroll
  for (int nt = 0; nt < 4; ++nt) {
#pragma unroll
    for (int rg = 0; rg < 4; ++rg) {
      att[((size_t)(b * SS + i0 + w * 16 + kg * 4 + rg)) * DD + h * DH + nt * 16 + m16] =
          f2bf(O[nt][rg] * linv[rg]);
    }
  }
}

// ---------------------------------------------------------------------------
// LayerNorm over y = bf16(ypre) + bf16(x from hb).
// ---------------------------------------------------------------------------
__global__ __launch_bounds__(256) void ln_kernel(const ushort* __restrict__ ypre,
                                                 const ushort* __restrict__ hb,
                                                 const float* __restrict__ gamma,
                                                 const float* __restrict__ beta,
                                                 float* __restrict__ out) {
  const int row = blockIdx.x;
  const int t = threadIdx.x;
  const int lane = t & 63, w = t >> 6;
  const ushort* yr = ypre + (size_t)row * DD;
  const ushort* xr = hb + ((size_t)((row >> 9) * TT + MM + (row & 511))) * DD;

  ushort4 yv = *(const ushort4*)(yr + t * 4);
  ushort4 xv = *(const ushort4*)(xr + t * 4);
  float v0 = bf2f(yv.x) + bf2f(xv.x), v1 = bf2f(yv.y) + bf2f(xv.y);
  float v2 = bf2f(yv.z) + bf2f(xv.z), v3 = bf2f(yv.w) + bf2f(xv.w);

  float s = v0 + v1 + v2 + v3;
  float ss = v0 * v0 + v1 * v1 + v2 * v2 + v3 * v3;
  __shared__ float rs[4], rss[4];
#pragma unroll
  for (int off = 32; off; off >>= 1) {
    s += __shfl_xor(s, off);
    ss += __shfl_xor(ss, off);
  }
  if (!lane) { rs[w] = s; rss[w] = ss; }
  __syncthreads();
  s = rs[0] + rs[1] + rs[2] + rs[3];
  ss = rss[0] + rss[1] + rss[2] + rss[3];
  const float mu = s * (1.f / DD);
  const float var = ss * (1.f / DD) - mu * mu;
  const float rstd = rsqrtf(var + 1e-5f);

  float4 g = *(const float4*)(gamma + t * 4);
  float4 be = *(const float4*)(beta + t * 4);
  float4 o;
  o.x = (v0 - mu) * rstd * g.x + be.x;
  o.y = (v1 - mu) * rstd * g.y + be.y;
  o.z = (v2 - mu) * rstd * g.z + be.z;
  o.w = (v3 - mu) * rstd * g.w + be.w;
  *(float4*)(out + (size_t)row * DD + t * 4) = o;
}

// ---------------------------------------------------------------------------
extern "C" void kernel_launch(void* const* d_in, const int* in_sizes, int n_in,
                              void* d_out, int out_size, void* d_ws, size_t ws_size,
                              hipStream_t stream) {
  const float* x = (const float*)d_in[0];
  const float* mem = (const float*)d_in[1];
  const float* R = (const float*)d_in[2];
  const float* u = (const float*)d_in[3];
  const float* tv = (const float*)d_in[4];
  const float* Wq = (const float*)d_in[5];
  const float* Wk = (const float*)d_in[6];
  const float* Wv = (const float*)d_in[7];
  const float* Wr = (const float*)d_in[8];
  const float* Wo = (const float*)d_in[9];
  const float* gamma = (const float*)d_in[10];
  const float* beta = (const float*)d_in[11];
  float* out = (float*)d_out;

  // ws layout (ushort units, 1M = 1<<20):
  ushort* hb = (ushort*)d_ws;                       // 8M  concat(mem,x) bf16
  ushort* Rb = hb + (8u << 20);                     // 1M
  ushort* Wqb = Rb + (1u << 20);                    // 1M
  ushort* Wkb = Wqb + (1u << 20);                   // 1M
  ushort* Wvb = Wkb + (1u << 20);                   // 1M
  ushort* Wrb = Wvb + (1u << 20);                   // 1M
  ushort* Wob = Wrb + (1u << 20);                   // 1M
  ushort* qu_b = Wob + (1u << 20);                  // 4M  (att aliases)
  ushort* kb = qu_b + (4u << 20);                   // 8M  (ypre bf16 aliases)
  ushort* vt = kb + (8u << 20);                     // 8M  V stored TRANSPOSED
  ushort* rb = vt + (8u << 20);                     // 1M
  ushort* att = qu_b;
  ushort* ypre = kb;  // kb dead after attention

  dim3 blk(256);

  // fused casts (14M elems / 8 / 256 = 7168 blocks)
  cast_all<<<dim3(7168), blk, 0, stream>>>(mem, x, R, Wq, Wk, Wv, Wr, Wo,
                                           hb, Rb, Wqb, Wkb, Wvb, Wrb, Wob);

  // fused q / kv / r projections (kv blocks compute k AND v; v transposed)
  gemm_qkvr<<<dim3(832), blk, 0, stream>>>(hb, Rb, Wqb, Wkb, Wvb, Wrb,
                                           qu_b, kb, vt, rb, u);

  // attention: 1D grid, longest blocks first; qt rebuilt from qu + (t-u)
  attn_mfma<<<dim3(BB * HH * 8), blk, 0, stream>>>(qu_b, kb, vt, rb, u, tv, att);

  gemm_wo<<<dim3(512), blk, 0, stream>>>(att, Wob, ypre);

  ln_kernel<<<dim3(BB * SS), blk, 0, stream>>>(ypre, hb, gamma, beta, out);
}

// Round 17
// 157.575 us; speedup vs baseline: 1.0683x; 1.0683x over previous
//
#include <hip/hip_runtime.h>
#include <math.h>

#define BB 8
#define SS 512
#define MM 512
#define TT 1024
#define DD 1024
#define HH 16
#define DH 64

typedef __attribute__((ext_vector_type(8))) short bf16x8;
typedef __attribute__((ext_vector_type(4))) float f32x4;

#define SCL2E 0.1803368801111f  /* 0.125 * log2(e) */
#define DTHR 11.5f              /* defer-max threshold in log2 units */

__device__ __forceinline__ ushort f2bf(float f) {
  union { float f; unsigned u; } x; x.f = f;
  unsigned r = x.u + 0x7fffu + ((x.u >> 16) & 1u);
  return (ushort)(r >> 16);
}
__device__ __forceinline__ float bf2f(ushort u) {
  return __builtin_bit_cast(float, ((unsigned)u) << 16);
}

__device__ __forceinline__ void stage16(void* lds, const void* g) {
  __builtin_amdgcn_global_load_lds((const __attribute__((address_space(1))) void*)g,
                                   (__attribute__((address_space(3))) void*)lds, 16, 0, 0);
}

template <int C>
__device__ __forceinline__ float dppf(float x) {
  return __builtin_bit_cast(float,
      __builtin_amdgcn_update_dpp(0, __builtin_bit_cast(int, x), C, 0xF, 0xF, true));
}
__device__ __forceinline__ float redmax16(float x) {
  x = fmaxf(x, dppf<0xB1>(x));
  x = fmaxf(x, dppf<0x4E>(x));
  x = fmaxf(x, dppf<0x141>(x));
  x = fmaxf(x, dppf<0x140>(x));
  return x;
}
__device__ __forceinline__ float redsum16(float x) {
  x += dppf<0xB1>(x);
  x += dppf<0x4E>(x);
  x += dppf<0x141>(x);
  x += dppf<0x140>(x);
  return x;
}
__device__ __forceinline__ float bperm_f(int byteaddr, float v) {
  return __builtin_bit_cast(float,
      __builtin_amdgcn_ds_bpermute(byteaddr, __builtin_bit_cast(int, v)));
}

// ---------------------------------------------------------------------------
// Fused fp32->bf16 casts (segment decode per block range).
// ---------------------------------------------------------------------------
__global__ __launch_bounds__(256) void cast_all(
    const float* __restrict__ mem, const float* __restrict__ x,
    const float* __restrict__ R, const float* __restrict__ Wq,
    const float* __restrict__ Wk, const float* __restrict__ Wv,
    const float* __restrict__ Wr, const float* __restrict__ Wo,
    ushort* __restrict__ hb, ushort* __restrict__ Rb, ushort* __restrict__ Wqb,
    ushort* __restrict__ Wkb, ushort* __restrict__ Wvb, ushort* __restrict__ Wrb,
    ushort* __restrict__ Wob) {
  const int M1 = 1 << 20;
  int i = (blockIdx.x * 256 + threadIdx.x) * 8;
  const float* src;
  ushort* dst;
  if (i < 4 * M1) {
    src = mem + i;
    dst = hb + (size_t)i + (size_t)(i >> 19) * 524288;
  } else if (i < 8 * M1) {
    int j = i - 4 * M1;
    src = x + j;
    dst = hb + (size_t)j + (size_t)(j >> 19) * 524288 + 524288;
  } else if (i < 9 * M1) {
    src = R + (i - 8 * M1);  dst = Rb + (i - 8 * M1);
  } else if (i < 10 * M1) {
    src = Wq + (i - 9 * M1); dst = Wqb + (i - 9 * M1);
  } else if (i < 11 * M1) {
    src = Wk + (i - 10 * M1); dst = Wkb + (i - 10 * M1);
  } else if (i < 12 * M1) {
    src = Wv + (i - 11 * M1); dst = Wvb + (i - 11 * M1);
  } else if (i < 13 * M1) {
    src = Wr + (i - 12 * M1); dst = Wrb + (i - 12 * M1);
  } else {
    src = Wo + (i - 13 * M1); dst = Wob + (i - 13 * M1);
  }
  float4 a = *(const float4*)(src);
  float4 c = *(const float4*)(src + 4);
  union { bf16x8 v; ushort u[8]; } pk;
  pk.u[0] = f2bf(a.x); pk.u[1] = f2bf(a.y); pk.u[2] = f2bf(a.z); pk.u[3] = f2bf(a.w);
  pk.u[4] = f2bf(c.x); pk.u[5] = f2bf(c.y); pk.u[6] = f2bf(c.z); pk.u[7] = f2bf(c.w);
  *(bf16x8*)(void*)dst = pk.v;
}

// ---------------------------------------------------------------------------
// Fused q/k/v/r projection GEMM (r14/r15-verified counted-vmcnt pipeline).
// ---------------------------------------------------------------------------
__global__ __launch_bounds__(256, 4) void gemm_qkvr(
    const ushort* __restrict__ hb, const ushort* __restrict__ Rbuf,
    const ushort* __restrict__ Wqb, const ushort* __restrict__ Wkb,
    const ushort* __restrict__ Wvb, const ushort* __restrict__ Wrb,
    ushort* __restrict__ qub,
    ushort* __restrict__ kbo, ushort* __restrict__ vtb, ushort* __restrict__ rbo,
    const float* __restrict__ uvec) {
  __shared__ ushort As0[4096], Bs0[4096], As1[4096], Bs1[4096];
  const int bid = (blockIdx.x & 7) * 168 + (blockIdx.x >> 3);
  const ushort* A;
  const ushort* W;
  ushort* C0 = nullptr;
  bool qadd = false, qslice = false, vmode = false;
  int mt, nx;
  if (bid < 256) {
    mt = bid >> 3; nx = bid & 7;
    A = hb; W = Wqb; C0 = qub; qadd = true; qslice = true;
  } else if (bid < 768) {
    int r = bid - 256; mt = r >> 3; nx = r & 7;
    A = hb; W = Wkb; C0 = kbo;
  } else if (bid < 1280) {
    int r = bid - 768; mt = r >> 3; nx = r & 7;
    A = hb; W = Wvb; C0 = vtb; vmode = true;
  } else {
    int r = bid - 1280; mt = r >> 3; nx = r & 7;
    A = Rbuf; W = Wrb; C0 = rbo;
  }
  const int m0 = mt * 128, n0 = nx * 128;

  const int t = threadIdx.x;
  const int w = t >> 6, l = t & 63;
  const int m16 = l & 15, kg = l >> 4;
  const int wr = w >> 1, wc = w & 1;

  const int c0 = t, c1 = t + 256;
  const int scol = (((t & 3) ^ ((t >> 3) & 3)) * 8);
  const ushort* asrc0;
  const ushort* asrc1;
  {
    int gm0 = m0 + (c0 >> 2), gm1 = m0 + (c1 >> 2);
    if (qslice) {
      asrc0 = A + ((size_t)((gm0 >> 9) * TT + MM + (gm0 & 511))) * DD + scol;
      asrc1 = A + ((size_t)((gm1 >> 9) * TT + MM + (gm1 & 511))) * DD + scol;
    } else {
      asrc0 = A + (size_t)gm0 * DD + scol;
      asrc1 = A + (size_t)gm1 * DD + scol;
    }
  }
  const ushort* bsrc0 = W + (size_t)(n0 + (c0 >> 2)) * DD + scol;
  const ushort* bsrc1 = W + (size_t)(n0 + (c1 >> 2)) * DD + scol;

  const int cbx = ((kg ^ ((m16 >> 1) & 3)) << 3);
  const int arow0 = (wr * 64 + m16) * 32 + cbx;
  const int brow0 = (wc * 64 + m16) * 32 + cbx;

  f32x4 acc[4][4];
#pragma unroll
  for (int mi = 0; mi < 4; ++mi)
#pragma unroll
    for (int ni = 0; ni < 4; ++ni) acc[mi][ni] = (f32x4){0.f, 0.f, 0.f, 0.f};

#define QKVR_STAGE(AS, BS, KOFF)                \
  do {                                          \
    stage16(AS + c0 * 8, asrc0 + (KOFF));       \
    stage16(AS + c1 * 8, asrc1 + (KOFF));       \
    stage16(BS + c0 * 8, bsrc0 + (KOFF));       \
    stage16(BS + c1 * 8, bsrc1 + (KOFF));       \
  } while (0)

#define QKVR_COMPUTE(AS, BS)                                                      \
  do {                                                                            \
    bf16x8 af[4], bfr[4];                                                         \
    _Pragma("unroll") for (int mi = 0; mi < 4; ++mi)                              \
        af[mi] = *(const bf16x8*)(const void*)&AS[arow0 + mi * 512];              \
    _Pragma("unroll") for (int ni = 0; ni < 4; ++ni)                              \
        bfr[ni] = *(const bf16x8*)(const void*)&BS[brow0 + ni * 512];             \
    _Pragma("unroll") for (int mi = 0; mi < 4; ++mi)                              \
        _Pragma("unroll") for (int ni = 0; ni < 4; ++ni)                          \
            acc[mi][ni] = __builtin_amdgcn_mfma_f32_16x16x32_bf16(                \
                af[mi], bfr[ni], acc[mi][ni], 0, 0, 0);                           \
  } while (0)

  QKVR_STAGE(As0, Bs0, 0);

#pragma unroll 1
  for (int kt = 0; kt < 32; kt += 2) {
    QKVR_STAGE(As1, Bs1, (kt + 1) << 5);
    asm volatile("s_waitcnt vmcnt(4)" ::: "memory");
    __builtin_amdgcn_s_barrier();
    QKVR_COMPUTE(As0, Bs0);
    __builtin_amdgcn_s_barrier();
    if (kt + 2 < 32) {
      QKVR_STAGE(As0, Bs0, (kt + 2) << 5);
      asm volatile("s_waitcnt vmcnt(4)" ::: "memory");
    } else {
      asm volatile("s_waitcnt vmcnt(0)" ::: "memory");
    }
    __builtin_amdgcn_s_barrier();
    QKVR_COMPUTE(As1, Bs1);
    __builtin_amdgcn_s_barrier();
  }
#undef QKVR_STAGE
#undef QKVR_COMPUTE

  const int rbase = m0 + wr * 64 + kg * 4;
  const int cbase = n0 + wc * 64 + m16;
  if (vmode) {
    const int bb = m0 >> 10;
    const int tt0 = (m0 & 1023) + wr * 64 + kg * 4;
#pragma unroll
    for (int mi = 0; mi < 4; ++mi)
#pragma unroll
      for (int ni = 0; ni < 4; ++ni) {
        ushort4 o;
        o.x = f2bf(acc[mi][ni][0]); o.y = f2bf(acc[mi][ni][1]);
        o.z = f2bf(acc[mi][ni][2]); o.w = f2bf(acc[mi][ni][3]);
        *(ushort4*)(C0 + ((size_t)(bb * 1024 + cbase + ni * 16) << 10) + tt0 + mi * 16) = o;
      }
  } else if (qadd) {
    float uv[4];
#pragma unroll
    for (int ni = 0; ni < 4; ++ni) uv[ni] = uvec[cbase + ni * 16];
#pragma unroll
    for (int mi = 0; mi < 4; ++mi)
#pragma unroll
      for (int ni = 0; ni < 4; ++ni)
#pragma unroll
        for (int rg = 0; rg < 4; ++rg)
          C0[(size_t)(rbase + mi * 16 + rg) * DD + cbase + ni * 16] = f2bf(acc[mi][ni][rg] + uv[ni]);
  } else {
#pragma unroll
    for (int mi = 0; mi < 4; ++mi)
#pragma unroll
      for (int ni = 0; ni < 4; ++ni)
#pragma unroll
        for (int rg = 0; rg < 4; ++rg)
          C0[(size_t)(rbase + mi * 16 + rg) * DD + cbase + ni * 16] = f2bf(acc[mi][ni][rg]);
  }
}

// ---------------------------------------------------------------------------
// MFMA GEMM for Wo: 128x64 tiles -> 512 blocks. Counted-vmcnt pipeline
// (r14 pattern, 3 loads/phase -> vmcnt(3), static double buffers, 24 KB LDS).
// XCD swizzle (512 = 8*64).
// ---------------------------------------------------------------------------
__global__ __launch_bounds__(256) void gemm_wo(const ushort* __restrict__ A,
                                               const ushort* __restrict__ W,
                                               ushort* __restrict__ Cb) {
  __shared__ ushort As0[4096], As1[4096], Bs0[2048], Bs1[2048];
  const int bid = (blockIdx.x & 7) * 64 + (blockIdx.x >> 3);
  const int mt = bid >> 4, nxt = bid & 15;
  const int m0 = mt * 128, n0 = nxt * 64;
  const int t = threadIdx.x;
  const int w = t >> 6, l = t & 63;
  const int m16 = l & 15, kg = l >> 4;
  const int wr = w >> 1, wc = w & 1;

  const int scol = (((t & 3) ^ ((t >> 3) & 3)) * 8);
  const ushort* asrc0 = A + (size_t)(m0 + (t >> 2)) * DD + scol;
  const ushort* asrc1 = A + (size_t)(m0 + 64 + (t >> 2)) * DD + scol;
  const ushort* bsrc0 = W + (size_t)(n0 + (t >> 2)) * DD + scol;

  const int cbx = ((kg ^ ((m16 >> 1) & 3)) << 3);
  const int arow0 = (wr * 64 + m16) * 32 + cbx;
  const int brow0 = (wc * 32 + m16) * 32 + cbx;

  f32x4 acc[4][2];
#pragma unroll
  for (int mi = 0; mi < 4; ++mi)
#pragma unroll
    for (int ni = 0; ni < 2; ++ni) acc[mi][ni] = (f32x4){0.f, 0.f, 0.f, 0.f};

#define WO_STAGE(AS, BS, KOFF)                    \
  do {                                            \
    stage16(AS + t * 8, asrc0 + (KOFF));          \
    stage16(AS + (t + 256) * 8, asrc1 + (KOFF));  \
    stage16(BS + t * 8, bsrc0 + (KOFF));          \
  } while (0)

#define WO_COMPUTE(AS, BS)                                                        \
  do {                                                                            \
    bf16x8 af[4], bfr[2];                                                         \
    _Pragma("unroll") for (int mi = 0; mi < 4; ++mi)                              \
        af[mi] = *(const bf16x8*)(const void*)&AS[arow0 + mi * 512];              \
    _Pragma("unroll") for (int ni = 0; ni < 2; ++ni)                              \
        bfr[ni] = *(const bf16x8*)(const void*)&BS[brow0 + ni * 512];             \
    _Pragma("unroll") for (int mi = 0; mi < 4; ++mi)                              \
        _Pragma("unroll") for (int ni = 0; ni < 2; ++ni)                          \
            acc[mi][ni] = __builtin_amdgcn_mfma_f32_16x16x32_bf16(                \
                af[mi], bfr[ni], acc[mi][ni], 0, 0, 0);                           \
  } while (0)

  WO_STAGE(As0, Bs0, 0);

#pragma unroll 1
  for (int kt = 0; kt < 32; kt += 2) {
    WO_STAGE(As1, Bs1, (kt + 1) << 5);
    asm volatile("s_waitcnt vmcnt(3)" ::: "memory");
    __builtin_amdgcn_s_barrier();
    WO_COMPUTE(As0, Bs0);
    __builtin_amdgcn_s_barrier();
    if (kt + 2 < 32) {
      WO_STAGE(As0, Bs0, (kt + 2) << 5);
      asm volatile("s_waitcnt vmcnt(3)" ::: "memory");
    } else {
      asm volatile("s_waitcnt vmcnt(0)" ::: "memory");
    }
    __builtin_amdgcn_s_barrier();
    WO_COMPUTE(As1, Bs1);
    __builtin_amdgcn_s_barrier();
  }
#undef WO_STAGE
#undef WO_COMPUTE

  const int rbase = m0 + wr * 64 + kg * 4;
  const int cbase = n0 + wc * 32 + m16;
#pragma unroll
  for (int mi = 0; mi < 4; ++mi)
#pragma unroll
    for (int ni = 0; ni < 2; ++ni)
#pragma unroll
      for (int rg = 0; rg < 4; ++rg)
        Cb[(size_t)(rbase + mi * 16 + rg) * DD + cbase + ni * 16] = f2bf(acc[mi][ni][rg]);
}

// ---------------------------------------------------------------------------
// MFMA flash attention: counted-vmcnt 2-phase pipeline (r15-verified).
// ---------------------------------------------------------------------------
__global__ __launch_bounds__(256) void attn_mfma(const ushort* __restrict__ qu,
                                                 const ushort* __restrict__ kb,
                                                 const ushort* __restrict__ vt,
                                                 const ushort* __restrict__ rb,
                                                 const float* __restrict__ uvec,
                                                 const float* __restrict__ tvec,
                                                 ushort* __restrict__ att) {
  const int w = threadIdx.x >> 6;
  const int l = threadIdx.x & 63;
  const int m16 = l & 15;
  const int kg = l >> 4;
  const int bid = blockIdx.x;
  const int it = 7 - (bid >> 7);         // longest (ntj=16) first
  const int bh = bid & 127;
  const int b = bh >> 4, h = bh & 15;
  const int i0 = it * 64;

  __shared__ ushort Ks0[4096], Ks1[4096];
  __shared__ ushort Vs0[4096], Vs1[4096];
  __shared__ ushort Rl[16384];
  __shared__ ushort plds[4][16][72];

  bf16x8 aqu[2], aqt[2];
  {
    const ushort* qrow = qu + ((size_t)(b * SS + i0 + w * 16 + m16)) * DD + h * DH + kg * 8;
    aqu[0] = *(const bf16x8*)(const void*)(qrow);
    aqu[1] = *(const bf16x8*)(const void*)(qrow + 32);
#pragma unroll
    for (int ks = 0; ks < 2; ++ks) {
      ushort* a = (ushort*)&aqt[ks];
      const ushort* qa = (const ushort*)&aqu[ks];
#pragma unroll
      for (int e = 0; e < 8; ++e) {
        const int col = h * DH + kg * 8 + ks * 32 + e;
        a[e] = f2bf(bf2f(qa[e]) + (tvec[col] - uvec[col]));
      }
    }
  }

  int baddr[4];
  bool bsel[4];
#pragma unroll
  for (int rg = 0; rg < 4; ++rg) {
    const int rw = kg * 4 + rg;
    baddr[rg] = (kg * 16 + ((m16 + 15 - rw) & 15)) << 2;
    bsel[rg] = m16 > rw;
  }

  const int c0 = threadIdx.x, c1 = threadIdx.x + 256;
  const int r0 = c0 >> 3, sc0 = ((c0 & 7) * 8) ^ ((r0 & 7) << 3);
  const int r1 = c1 >> 3, sc1 = ((c1 & 7) * 8) ^ ((r1 & 7) << 3);
  const ushort* kp0 = kb + ((size_t)(b * TT) + r0) * DD + h * DH + sc0;
  const ushort* kp1 = kb + ((size_t)(b * TT) + r1) * DD + h * DH + sc1;
  const ushort* vp0 = vt + ((size_t)(b * 1024 + h * DH + r0)) * 1024 + sc0;
  const ushort* vp1 = vt + ((size_t)(b * 1024 + h * DH + r1)) * 1024 + sc1;

  const int cb0 = (kg * 8) ^ ((m16 & 7) << 3);
  const int cb1 = (kg * 8 + 32) ^ ((m16 & 7) << 3);
  int slot64[5];
#pragma unroll
  for (int f = 0; f < 5; ++f)
    slot64[f] = ((496 - i0 - w * 16 + m16 + f * 16) & 255) << 6;

  {
    const int base0 = 448 - i0;
#pragma unroll
    for (int kk = 0; kk < 4; ++kk) {
      int c = threadIdx.x + kk * 256;
      int ro = c >> 3, cc = c & 7;
      int p = base0 + ro;
      int slot = p & 255;
      stage16(Rl + slot * 64 + cc * 8,
              rb + (size_t)p * DD + h * DH + ((cc * 8) ^ ((ro & 7) << 3)));
    }
  }
  stage16(Ks0 + c0 * 8, kp0);
  stage16(Ks0 + c1 * 8, kp1);
  stage16(Vs0 + c0 * 8, vp0);
  stage16(Vs0 + c1 * 8, vp1);
  kp0 += (size_t)64 * DD; kp1 += (size_t)64 * DD;
  vp0 += 64; vp1 += 64;

  f32x4 O[4];
  float mrow[4], lrow[4];
#pragma unroll
  for (int nt = 0; nt < 4; ++nt) O[nt] = (f32x4){0.f, 0.f, 0.f, 0.f};
#pragma unroll
  for (int rg = 0; rg < 4; ++rg) { mrow[rg] = -1e30f; lrow[rg] = 0.f; }

  const int ntj = it + 9;

  auto stage_next = [&](ushort* KN, ushort* VN, int jt) {
    stage16(KN + c0 * 8, kp0);
    stage16(KN + c1 * 8, kp1);
    kp0 += (size_t)64 * DD; kp1 += (size_t)64 * DD;
    stage16(VN + c0 * 8, vp0);
    stage16(VN + c1 * 8, vp1);
    vp0 += 64; vp1 += 64;
    const int pstart = 576 + jt * 64 - i0;
#pragma unroll
    for (int kk = 0; kk < 2; ++kk) {
      int c = threadIdx.x + kk * 256;
      int ro = c >> 3, cc = c & 7;
      int p = pstart + ro;
      int pc = p < 1023 ? p : 1023;
      int slot = p & 255;
      stage16(Rl + slot * 64 + cc * 8,
              rb + (size_t)pc * DD + h * DH + ((cc * 8) ^ ((ro & 7) << 3)));
    }
  };

  auto compute_tile = [&](const ushort* kbase, const ushort* vbase, int jt) {
    const int j0 = jt * 64;
    f32x4 ac[4];
    __builtin_amdgcn_s_setprio(1);
#pragma unroll
    for (int nt = 0; nt < 4; ++nt) {
      ac[nt] = (f32x4){0.f, 0.f, 0.f, 0.f};
      const int row = nt * 16 + m16;
#pragma unroll
      for (int ks = 0; ks < 2; ++ks) {
        bf16x8 bk = *(const bf16x8*)(const void*)(kbase + row * 64 + (ks == 0 ? cb0 : cb1));
        ac[nt] = __builtin_amdgcn_mfma_f32_16x16x32_bf16(aqu[ks], bk, ac[nt], 0, 0, 0);
      }
    }
    f32x4 bd[5];
#pragma unroll
    for (int f = 0; f < 5; ++f) {
      f32x4 z = (f32x4){0.f, 0.f, 0.f, 0.f};
      bf16x8 b0 = *(const bf16x8*)(const void*)(Rl + slot64[f] + cb0);
      z = __builtin_amdgcn_mfma_f32_16x16x32_bf16(aqt[0], b0, z, 0, 0, 0);
      bf16x8 b1 = *(const bf16x8*)(const void*)(Rl + slot64[f] + cb1);
      bd[f] = __builtin_amdgcn_mfma_f32_16x16x32_bf16(aqt[1], b1, z, 0, 0, 0);
    }
    __builtin_amdgcn_s_setprio(0);
#pragma unroll
    for (int f = 0; f < 5; ++f) slot64[f] = (slot64[f] + 4096) & 16383;

    float sca[4][4];
#pragma unroll
    for (int rg = 0; rg < 4; ++rg) {
      float rr[5];
#pragma unroll
      for (int f = 0; f < 5; ++f) rr[f] = bperm_f(baddr[rg], bd[f][rg]);
#pragma unroll
      for (int nt = 0; nt < 4; ++nt) {
        float bdv = bsel[rg] ? rr[nt + 1] : rr[nt];
        sca[nt][rg] = (ac[nt][rg] + bdv) * SCL2E;
      }
    }
    if (jt == ntj - 1) {
#pragma unroll
      for (int rg = 0; rg < 4; ++rg) {
        const int jmax = i0 + w * 16 + kg * 4 + rg + MM;
#pragma unroll
        for (int nt = 0; nt < 4; ++nt)
          sca[nt][rg] = (j0 + nt * 16 + m16 <= jmax) ? sca[nt][rg] : -1e30f;
      }
    }

    float pmax[4];
#pragma unroll
    for (int rg = 0; rg < 4; ++rg) {
      float pm = fmaxf(fmaxf(sca[0][rg], sca[1][rg]), fmaxf(sca[2][rg], sca[3][rg]));
      pmax[rg] = redmax16(pm);
    }
    bool grow = false;
#pragma unroll
    for (int rg = 0; rg < 4; ++rg) grow = grow || (pmax[rg] > mrow[rg] + DTHR);
    if (__any(grow)) {
#pragma unroll
      for (int rg = 0; rg < 4; ++rg) {
        float mnew = fmaxf(mrow[rg], pmax[rg]);
        float scale = __builtin_amdgcn_exp2f(mrow[rg] - mnew);
        mrow[rg] = mnew;
        lrow[rg] *= scale;
#pragma unroll
        for (int nt = 0; nt < 4; ++nt) O[nt][rg] *= scale;
      }
    }

#pragma unroll
    for (int rg = 0; rg < 4; ++rg) {
      float ps = 0.f;
#pragma unroll
      for (int nt = 0; nt < 4; ++nt) {
        float p = __builtin_amdgcn_exp2f(sca[nt][rg] - mrow[rg]);
        ps += p;
        plds[w][kg * 4 + rg][nt * 16 + m16] = f2bf(p);
      }
      lrow[rg] += redsum16(ps);
    }

    __builtin_amdgcn_s_setprio(1);
#pragma unroll
    for (int ks = 0; ks < 2; ++ks) {
      bf16x8 pa = *(const bf16x8*)(const void*)&plds[w][m16][kg * 8 + ks * 32];
#pragma unroll
      for (int nt = 0; nt < 4; ++nt) {
        bf16x8 vf = *(const bf16x8*)(const void*)(vbase + (nt * 16 + m16) * 64 + (ks == 0 ? cb0 : cb1));
        O[nt] = __builtin_amdgcn_mfma_f32_16x16x32_bf16(pa, vf, O[nt], 0, 0, 0);
      }
    }
    __builtin_amdgcn_s_setprio(0);
  };

  int jt = 0;
  for (;;) {
    {
      if (jt + 1 < ntj) {
        stage_next(Ks1, Vs1, jt);
        asm volatile("s_waitcnt vmcnt(6)" ::: "memory");
      } else {
        asm volatile("s_waitcnt vmcnt(0)" ::: "memory");
      }
      __builtin_amdgcn_s_barrier();
      compute_tile(Ks0, Vs0, jt);
      if (jt + 1 == ntj) break;
      __builtin_amdgcn_s_barrier();
      ++jt;
    }
    {
      if (jt + 1 < ntj) {
        stage_next(Ks0, Vs0, jt);
        asm volatile("s_waitcnt vmcnt(6)" ::: "memory");
      } else {
        asm volatile("s_waitcnt vmcnt(0)" ::: "memory");
      }
      __builtin_amdgcn_s_barrier();
      compute_tile(Ks1, Vs1, jt);
      if (jt + 1 == ntj) break;
      __builtin_amdgcn_s_barrier();
      ++jt;
    }
  }

  float linv[4];
#pragma unroll
  for (int rg = 0; rg < 4; ++rg) linv[rg] = 1.f / lrow[rg];
#pragma unroll
  for (int nt = 0; nt < 4; ++nt) {
#pragma unroll
    for (int rg = 0; rg < 4; ++rg) {
      att[((size_t)(b * SS + i0 + w * 16 + kg * 4 + rg)) * DD + h * DH + nt * 16 + m16] =
          f2bf(O[nt][rg] * linv[rg]);
    }
  }
}

// ---------------------------------------------------------------------------
// LayerNorm over y = bf16(ypre) + bf16(x from hb).
// ---------------------------------------------------------------------------
__global__ __launch_bounds__(256) void ln_kernel(const ushort* __restrict__ ypre,
                                                 const ushort* __restrict__ hb,
                                                 const float* __restrict__ gamma,
                                                 const float* __restrict__ beta,
                                                 float* __restrict__ out) {
  const int row = blockIdx.x;
  const int t = threadIdx.x;
  const int lane = t & 63, w = t >> 6;
  const ushort* yr = ypre + (size_t)row * DD;
  const ushort* xr = hb + ((size_t)((row >> 9) * TT + MM + (row & 511))) * DD;

  ushort4 yv = *(const ushort4*)(yr + t * 4);
  ushort4 xv = *(const ushort4*)(xr + t * 4);
  float v0 = bf2f(yv.x) + bf2f(xv.x), v1 = bf2f(yv.y) + bf2f(xv.y);
  float v2 = bf2f(yv.z) + bf2f(xv.z), v3 = bf2f(yv.w) + bf2f(xv.w);

  float s = v0 + v1 + v2 + v3;
  float ss = v0 * v0 + v1 * v1 + v2 * v2 + v3 * v3;
  __shared__ float rs[4], rss[4];
#pragma unroll
  for (int off = 32; off; off >>= 1) {
    s += __shfl_xor(s, off);
    ss += __shfl_xor(ss, off);
  }
  if (!lane) { rs[w] = s; rss[w] = ss; }
  __syncthreads();
  s = rs[0] + rs[1] + rs[2] + rs[3];
  ss = rss[0] + rss[1] + rss[2] + rss[3];
  const float mu = s * (1.f / DD);
  const float var = ss * (1.f / DD) - mu * mu;
  const float rstd = rsqrtf(var + 1e-5f);

  float4 g = *(const float4*)(gamma + t * 4);
  float4 be = *(const float4*)(beta + t * 4);
  float4 o;
  o.x = (v0 - mu) * rstd * g.x + be.x;
  o.y = (v1 - mu) * rstd * g.y + be.y;
  o.z = (v2 - mu) * rstd * g.z + be.z;
  o.w = (v3 - mu) * rstd * g.w + be.w;
  *(float4*)(out + (size_t)row * DD + t * 4) = o;
}

// ---------------------------------------------------------------------------
extern "C" void kernel_launch(void* const* d_in, const int* in_sizes, int n_in,
                              void* d_out, int out_size, void* d_ws, size_t ws_size,
                              hipStream_t stream) {
  const float* x = (const float*)d_in[0];
  const float* mem = (const float*)d_in[1];
  const float* R = (const float*)d_in[2];
  const float* u = (const float*)d_in[3];
  const float* tv = (const float*)d_in[4];
  const float* Wq = (const float*)d_in[5];
  const float* Wk = (const float*)d_in[6];
  const float* Wv = (const float*)d_in[7];
  const float* Wr = (const float*)d_in[8];
  const float* Wo = (const float*)d_in[9];
  const float* gamma = (const float*)d_in[10];
  const float* beta = (const float*)d_in[11];
  float* out = (float*)d_out;

  // ws layout (ushort units, 1M = 1<<20):
  ushort* hb = (ushort*)d_ws;                       // 8M  concat(mem,x) bf16
  ushort* Rb = hb + (8u << 20);                     // 1M
  ushort* Wqb = Rb + (1u << 20);                    // 1M
  ushort* Wkb = Wqb + (1u << 20);                   // 1M
  ushort* Wvb = Wkb + (1u << 20);                   // 1M
  ushort* Wrb = Wvb + (1u << 20);                   // 1M
  ushort* Wob = Wrb + (1u << 20);                   // 1M
  ushort* qu_b = Wob + (1u << 20);                  // 4M  (att aliases)
  ushort* kb = qu_b + (4u << 20);                   // 8M  (ypre bf16 aliases)
  ushort* vt = kb + (8u << 20);                     // 8M  V stored TRANSPOSED
  ushort* rb = vt + (8u << 20);                     // 1M
  ushort* att = qu_b;
  ushort* ypre = kb;  // kb dead after attention

  dim3 blk(256);

  // fused casts (14M elems / 8 / 256 = 7168 blocks)
  cast_all<<<dim3(7168), blk, 0, stream>>>(mem, x, R, Wq, Wk, Wv, Wr, Wo,
                                           hb, Rb, Wqb, Wkb, Wvb, Wrb, Wob);

  // fused q/k/v/r projections (V written transposed into vt; q = acc+u only)
  gemm_qkvr<<<dim3(1344), blk, 0, stream>>>(hb, Rb, Wqb, Wkb, Wvb, Wrb,
                                            qu_b, kb, vt, rb, u);

  // attention: 1D grid, longest blocks first; qt rebuilt from qu + (t-u)
  attn_mfma<<<dim3(BB * HH * 8), blk, 0, stream>>>(qu_b, kb, vt, rb, u, tv, att);

  gemm_wo<<<dim3(512), blk, 0, stream>>>(att, Wob, ypre);

  ln_kernel<<<dim3(BB * SS), blk, 0, stream>>>(ypre, hb, gamma, beta, out);
}